// Round 12
// baseline (1916.895 us; speedup 1.0000x reference)
//
#include <hip/hip_runtime.h>
#include <hip/hip_bf16.h>

// Bidirectional LSTM, B=32 T=512 D=H=512. f32 I/O, bf16 MFMA internally.
//
// R18 = R17 protocol VERBATIM, batch split deepened again: 8 independent
//       chains per direction (4 batches each). Grid (32, 2, 8) = 512 wgs
//       = 2 wgs/CU (LDS 2x52.5<=160KB, VGPR 2x~145<=512/SIMD;
//       __launch_bounds__(256,2)).
//  - Lever validated twice (R16: 2110->1786, R17: 1786->1446): smaller
//    per-step sweep per consumer (now 4 loads/thread, 8KB/chain-step) +
//    more chains staggering LLC bursts (16 total) + co-resident wg pairs
//    absorb each other's spin-sleep cycles.
//  - M=16 MFMA tile has 4 valid batch rows; rows 4-15 of xA/hA zeroed once
//    -> dead rows compute zeros, discarded. MFMA is <10% of step time.
//  - Everything else verbatim R9/R16/R17: step ordering, coalesced lane+64j
//    dense sweep, tagged 8B payloads, scattered-dword hA staging, 2
//    lgkm-only barriers/step, coalesced h/out stores.

typedef __bf16 bf16;
typedef __attribute__((ext_vector_type(8))) __bf16 bf16x8;
typedef __attribute__((ext_vector_type(4))) float f32x4;
typedef unsigned long long u64;

__device__ __forceinline__ float sigmoidf_(float x) {
  return 1.f / (1.f + __expf(-x));
}
__device__ __forceinline__ float tanhf_(float x) {
  float e = __expf(-2.f * fabsf(x));
  return copysignf((1.f - e) / (1.f + e), x);
}
__device__ __forceinline__ u64 ald64(const u64* p) {
  return __hip_atomic_load(p, __ATOMIC_RELAXED, __HIP_MEMORY_SCOPE_AGENT);
}
__device__ __forceinline__ void ast64(u64* p, u64 v) {
  __hip_atomic_store(p, v, __ATOMIC_RELAXED, __HIP_MEMORY_SCOPE_AGENT);
}
__device__ __forceinline__ bf16x8 cvt8v(float4 a, float4 b) {
  bf16x8 v;
  v[0] = (bf16)a.x; v[1] = (bf16)a.y; v[2] = (bf16)a.z; v[3] = (bf16)a.w;
  v[4] = (bf16)b.x; v[5] = (bf16)b.y; v[6] = (bf16)b.z; v[7] = (bf16)b.w;
  return v;
}
// Barrier with LDS-visibility only: does NOT drain vmcnt.
__device__ __forceinline__ void bar_lgkm() {
  asm volatile("s_waitcnt lgkmcnt(0)\n\ts_barrier" ::: "memory");
}

// ---------------- lengths ----------------
__global__ void lengths_kernel(const int* __restrict__ mask, int* __restrict__ lengths) {
  __shared__ int part[32][8];
  int t = threadIdx.x;
  int b = t >> 3, sub = t & 7;
  int s = 0;
#pragma unroll 8
  for (int k = 0; k < 64; ++k) s += mask[b * 512 + sub + 8 * k];
  part[b][sub] = s;
  __syncthreads();
  if (sub == 0) {
    int tot = 0;
#pragma unroll
    for (int k = 0; k < 8; ++k) tot += part[b][k];
    lengths[b] = tot;
  }
}

// ---------------- fused persistent LSTM ----------------
__global__ __launch_bounds__(256, 2) void lstm_fused(
    const float* __restrict__ x,                                  // [32][512][512] f32
    const float* __restrict__ Wih_f, const float* __restrict__ bih_f,
    const float* __restrict__ Whh_f,
    const float* __restrict__ Wih_b, const float* __restrict__ bih_b,
    const float* __restrict__ Whh_b,
    const int* __restrict__ lengths,
    u64* __restrict__ hbuf,             // [2 dir][2 par][32 batch][256] u64 entries
    float* __restrict__ out) {          // [32][512][1024] f32
  const int s = blockIdx.x;             // h-col slice: cols [16s, 16s+16)
  const int dir = blockIdx.y;
  const int grp = blockIdx.z;           // batch group: batches [4g, 4g+4)
  const float* Wih = dir ? Wih_b : Wih_f;
  const float* Whh = dir ? Whh_b : Whh_f;
  const float* bih = dir ? bih_b : bih_f;
  const int b0 = grp * 4;               // first batch of this chain

  const int tid = threadIdx.x;
  const int lane = tid & 63, wave = tid >> 6;
  const int l15 = lane & 15, quad = lane >> 4;

  // 16 rows allocated (MFMA A-tile is M=16); rows 4-15 zeroed once.
  __shared__ __align__(16) bf16 xA[2][16 * 512];  // 2x16 KB
  __shared__ __align__(16) bf16 hA[16 * 512];     // 16 KB
  __shared__ float vbuf[4][16][17];
  __shared__ int lenL[4];

  // Weight slices f32 -> bf16 registers (wave = gate; B-frag n=l15).
  bf16x8 wih[16], whh[16];
  {
    int grow = wave * 512 + s * 16 + l15;
#pragma unroll
    for (int k = 0; k < 16; ++k) {
      const float* pw = Wih + (size_t)grow * 512 + k * 32 + quad * 8;
      const float* ph = Whh + (size_t)grow * 512 + k * 32 + quad * 8;
      wih[k] = cvt8v(*(const float4*)pw, *(const float4*)(pw + 4));
      whh[k] = cvt8v(*(const float4*)ph, *(const float4*)(ph + 4));
    }
  }
  const float bv = bih[wave * 512 + s * 16 + l15];
  if (tid < 4) lenL[tid] = lengths[b0 + tid];

  // Zero dead rows 4-15 of xA[0], xA[1], hA (one-time; 36KB total).
  {
    // 3 buffers x 12 rows x 512 bf16 = 18432 bf16 = 2304 x 16B chunks.
    for (int c = tid; c < 2304; c += 256) {
      int buf = c / 768, rc = c - buf * 768;
      int r = rc >> 6, off = (rc & 63) * 8;
      bf16* dst = (buf == 0) ? (xA[0] + (4 + r) * 512 + off)
                : (buf == 1) ? (xA[1] + (4 + r) * 512 + off)
                             : (hA + (4 + r) * 512 + off);
      *(ulonglong2*)dst = make_ulonglong2(0ull, 0ull);
    }
  }
  __syncthreads();

  // Cell mapping (threads 0-31): cb = group-local batch, cj = col pair.
  const int cb = tid >> 3, cj = (tid & 7) * 2;
  const int lenR0 = lenL[tid >> 6];     // staging chunk's batch = tid>>6
  const int lenO = (tid < 32) ? lenL[cb] : 0;

  float creg0 = 0.f, creg1 = 0.f;
  u64* hb = hbuf + (size_t)dir * (2 * 32 * 256);

  // Prologue: load x(0), stage xA[0], then issue prefetch of x(1).
  // One 32B chunk per thread: 4 batches x 64 chunks = 256 chunks.
  float4 xp0, xp1;
  {
    int m = tid >> 6, kbp = tid & 63;
    int kb = kbp ^ (m & 7);
    int tr = (dir == 0) ? 0 : ((511 + lenR0) & 511);
    const float4* p = (const float4*)(x + ((size_t)(b0 + m) * 512 + tr) * 512 + kb * 8);
    xp0 = p[0]; xp1 = p[1];
    *(bf16x8*)(xA[0] + tid * 8) = cvt8v(xp0, xp1);
    tr = (dir == 0) ? 1 : ((510 + lenR0) & 511);
    p = (const float4*)(x + ((size_t)(b0 + m) * 512 + tr) * 512 + kb * 8);
    xp0 = p[0]; xp1 = p[1];
  }
  bar_lgkm();  // xA[0] staged

  for (int step = 0; step < 512; ++step) {
    const int par = step & 1;
    const u64* hprev = hb + (size_t)par * (32 * 256);
    u64* hnext = hb + (size_t)(par ^ 1) * (32 * 256);
    const bf16* xcur = xA[par];
    bf16* xnxt = xA[par ^ 1];

    // ---- (1) stage xA(t+1) from regs ----
    if (step < 511) {
      *(bf16x8*)(xnxt + tid * 8) = cvt8v(xp0, xp1);
    }
    // ---- (2) x(t+2) prefetch issue (R9 position) ----
    if (step < 510) {
      int m = tid >> 6, kbp = tid & 63;
      int kb = kbp ^ (m & 7);
      int tr = (dir == 0) ? (step + 2) : ((509 - step + lenR0) & 511);
      const float4* p = (const float4*)(x + ((size_t)(b0 + m) * 512 + tr) * 512 + kb * 8);
      xp0 = p[0]; xp1 = p[1];
    }

    // ---- (3) x-part MFMAs: v = x@Wih^T + bias (one M=16 tile) ----
    f32x4 acc0 = {bv, bv, bv, bv};
#pragma unroll
    for (int k = 0; k < 16; ++k) {
      int kb = k * 4 + quad;
      int sw = (kb ^ (l15 & 7)) * 8;
      bf16x8 ax0 = *(const bf16x8*)(xcur + l15 * 512 + sw);
      acc0 = __builtin_amdgcn_mfma_f32_16x16x32_bf16(ax0, wih[k], acc0, 0, 0, 0);
    }
    __builtin_amdgcn_sched_barrier(0);

    // ---- (4) poll (R9 verbatim): coalesced dense batched re-sweep ----
    // wave w covers group-local batch w; lane reads entries lane+64j
    // (512B contiguous per load instruction).
    u64 hv[4];
    {
      const unsigned target = (unsigned)step;
      const u64* rp = hprev + (size_t)(b0 + wave) * 256 + lane;
      while (true) {
#pragma unroll
        for (int j = 0; j < 4; ++j) hv[j] = ald64(rp + 64 * j);
        int ok = 1;
#pragma unroll
        for (int j = 0; j < 4; ++j)
          ok &= (int)((unsigned)(hv[j] >> 32) >= target);
        if (__all(ok)) break;
        __builtin_amdgcn_s_sleep(1);
      }
    }

    // ---- (5) stage payloads -> swizzled hA (R9 verbatim layout) ----
    {
      int m = wave;                             // group-local batch [0,4)
#pragma unroll
      for (int j = 0; j < 4; ++j) {
        int b8 = (lane >> 2) + 16 * j;          // 8-col block of col 2*(lane+64j)
        int b8s = b8 ^ (m & 7);                 // same XOR swizzle as MFMA reads
        *(unsigned*)(hA + m * 512 + b8s * 8 + 2 * (lane & 3)) = (unsigned)hv[j];
      }
    }
    bar_lgkm();  // C: hA + xnxt visible (x prefetch rides through)

    // ---- (6) h-part MFMAs: v += h@Whh^T ----
#pragma unroll
    for (int k = 0; k < 16; ++k) {
      int kb = k * 4 + quad;
      int sw = (kb ^ (l15 & 7)) * 8;
      bf16x8 ah0 = *(const bf16x8*)(hA + l15 * 512 + sw);
      acc0 = __builtin_amdgcn_mfma_f32_16x16x32_bf16(ah0, whh[k], acc0, 0, 0, 0);
    }
#pragma unroll
    for (int r = 0; r < 4; ++r)
      vbuf[wave][quad * 4 + r][l15] = acc0[r];
    bar_lgkm();  // D: vbuf ready

    // ---- (7) cell + stores: threads 0-31 (4 batches x 8 col-pairs) ----
    if (tid < 32) {
      float i0 = vbuf[0][cb][cj],     f0 = vbuf[1][cb][cj];
      float g0 = vbuf[2][cb][cj],     o0 = vbuf[3][cb][cj];
      float i1 = vbuf[0][cb][cj + 1], f1 = vbuf[1][cb][cj + 1];
      float g1 = vbuf[2][cb][cj + 1], o1 = vbuf[3][cb][cj + 1];
      float c0 = sigmoidf_(f0) * creg0 + sigmoidf_(i0) * tanhf_(g0);
      float c1 = sigmoidf_(f1) * creg1 + sigmoidf_(i1) * tanhf_(g1);
      creg0 = c0; creg1 = c1;
      float h0 = tanhf_(c0) * sigmoidf_(o0);
      float h1 = tanhf_(c1) * sigmoidf_(o1);

      // tagged h store: coalesced 64B line per 8 lanes
      unsigned ulo = (unsigned)__builtin_bit_cast(unsigned short, (bf16)h0);
      unsigned uhi = (unsigned)__builtin_bit_cast(unsigned short, (bf16)h1);
      u64 pk = ((u64)(unsigned)(step + 1) << 32) | (u64)(ulo | (uhi << 16));
      ast64(hnext + (size_t)(b0 + cb) * 256 + s * 8 + (tid & 7), pk);

      // out store (coalesced 64B per 8-thread group)
      int tr = (dir == 0) ? step : ((511 - step + lenO) & 511);
      *(float2*)(out + (size_t)((b0 + cb) * 512 + tr) * 1024 + dir * 512 + s * 16 + cj) =
          make_float2(h0, h1);
    }
  }
}

extern "C" void kernel_launch(void* const* d_in, const int* in_sizes, int n_in,
                              void* d_out, int out_size, void* d_ws, size_t ws_size,
                              hipStream_t stream) {
  (void)in_sizes; (void)n_in; (void)out_size; (void)ws_size;
  const float* x    = (const float*)d_in[0];
  const int*   mask = (const int*)  d_in[1];
  const float* Wihf = (const float*)d_in[2];
  const float* bihf = (const float*)d_in[3];
  const float* Whhf = (const float*)d_in[4];
  const float* Wihb = (const float*)d_in[5];
  const float* bihb = (const float*)d_in[6];
  const float* Whhb = (const float*)d_in[7];
  float* out = (float*)d_out;

  char* ws = (char*)d_ws;
  u64* hbuf = (u64*)ws;                          // 2*2*32*256*8 = 262144 B
  int* lengths = (int*)(ws + 262144);            // 128 B
  const size_t head = 262144;

  hipMemsetAsync(d_ws, 0, head, stream);  // zero tags + h0 = c0 = 0 every call
  lengths_kernel<<<1, 256, 0, stream>>>(mask, lengths);
  lstm_fused<<<dim3(32, 2, 8), 256, 0, stream>>>(
      x, Wihf, bihf, Whhf, Wihb, bihb, Whhb, lengths, hbuf, out);
}

// Round 13
// 1480.904 us; speedup vs baseline: 1.2944x; 1.2944x over previous
//
#include <hip/hip_runtime.h>
#include <hip/hip_bf16.h>

// Bidirectional LSTM, B=32 T=512 D=H=512. f32 I/O, bf16 MFMA internally.
//
// R19 = R17 VERBATIM (best: 1446us; 8 chains x 32 col-wgs, 1 wg/CU) with
//       one change: XCD-affine chain placement via flat-grid swizzle.
//  - Dispatch assigns wg i -> XCD i%8 (round-robin). Flat grid of 256 with
//    chain = bid%8, s = bid/8 gives every wg of a chain the same residue
//    -> one chain per XCD (32 wgs = that XCD's 32 CUs).
//    (a) agent-scope h-exchange per chain stays XCD-local (shorter path to
//        coherence point, less cross-die convoy jitter);
//    (b) x-prefetch reads become XCD-local (L2 caches only the chain's 8
//        batches = 8MB slice) -> FETCH_SIZE should drop;
//    (c) poll traffic per LLC region from one XCD instead of eight.
//    Pure index remap: correctness independent of actual XCD mapping.
//  - R18 lesson encoded: 2 wgs/CU co-residency hurts (spin loops steal
//    issue slots; VGPR squeezed to 128 -> spills). Stay at 1 wg/CU.
//  - Everything else verbatim R17: 4 waves/wg, 16 weight rows/wave in
//    128 VGPRs, M=16 tile with 8 valid batch rows (rows 8-15 zeroed),
//    R9 step ordering, coalesced lane+64j dense sweep, tagged 8B payloads,
//    scattered-dword hA staging, 2 lgkm-only barriers/step.

typedef __bf16 bf16;
typedef __attribute__((ext_vector_type(8))) __bf16 bf16x8;
typedef __attribute__((ext_vector_type(4))) float f32x4;
typedef unsigned long long u64;

__device__ __forceinline__ float sigmoidf_(float x) {
  return 1.f / (1.f + __expf(-x));
}
__device__ __forceinline__ float tanhf_(float x) {
  float e = __expf(-2.f * fabsf(x));
  return copysignf((1.f - e) / (1.f + e), x);
}
__device__ __forceinline__ u64 ald64(const u64* p) {
  return __hip_atomic_load(p, __ATOMIC_RELAXED, __HIP_MEMORY_SCOPE_AGENT);
}
__device__ __forceinline__ void ast64(u64* p, u64 v) {
  __hip_atomic_store(p, v, __ATOMIC_RELAXED, __HIP_MEMORY_SCOPE_AGENT);
}
__device__ __forceinline__ bf16x8 cvt8v(float4 a, float4 b) {
  bf16x8 v;
  v[0] = (bf16)a.x; v[1] = (bf16)a.y; v[2] = (bf16)a.z; v[3] = (bf16)a.w;
  v[4] = (bf16)b.x; v[5] = (bf16)b.y; v[6] = (bf16)b.z; v[7] = (bf16)b.w;
  return v;
}
// Barrier with LDS-visibility only: does NOT drain vmcnt.
__device__ __forceinline__ void bar_lgkm() {
  asm volatile("s_waitcnt lgkmcnt(0)\n\ts_barrier" ::: "memory");
}

// ---------------- lengths ----------------
__global__ void lengths_kernel(const int* __restrict__ mask, int* __restrict__ lengths) {
  __shared__ int part[32][8];
  int t = threadIdx.x;
  int b = t >> 3, sub = t & 7;
  int s = 0;
#pragma unroll 8
  for (int k = 0; k < 64; ++k) s += mask[b * 512 + sub + 8 * k];
  part[b][sub] = s;
  __syncthreads();
  if (sub == 0) {
    int tot = 0;
#pragma unroll
    for (int k = 0; k < 8; ++k) tot += part[b][k];
    lengths[b] = tot;
  }
}

// ---------------- fused persistent LSTM ----------------
__global__ __launch_bounds__(256, 1) void lstm_fused(
    const float* __restrict__ x,                                  // [32][512][512] f32
    const float* __restrict__ Wih_f, const float* __restrict__ bih_f,
    const float* __restrict__ Whh_f,
    const float* __restrict__ Wih_b, const float* __restrict__ bih_b,
    const float* __restrict__ Whh_b,
    const int* __restrict__ lengths,
    u64* __restrict__ hbuf,             // [2 dir][2 par][32 batch][256] u64 entries
    float* __restrict__ out) {          // [32][512][1024] f32
  // XCD-affine decode: chain = bid%8 (one chain per XCD), s = bid/8.
  const int bid = blockIdx.x;
  const int chain = bid & 7;
  const int s = bid >> 3;               // h-col slice: cols [16s, 16s+16)
  const int dir = chain & 1;
  const int grp = chain >> 1;           // batch group: batches [8g, 8g+8)
  const float* Wih = dir ? Wih_b : Wih_f;
  const float* Whh = dir ? Whh_b : Whh_f;
  const float* bih = dir ? bih_b : bih_f;
  const int b0 = grp * 8;               // first batch of this chain

  const int tid = threadIdx.x;
  const int lane = tid & 63, wave = tid >> 6;
  const int l15 = lane & 15, quad = lane >> 4;

  // 16 rows allocated (MFMA A-tile is M=16); rows 8-15 zeroed once.
  __shared__ __align__(16) bf16 xA[2][16 * 512];  // 2x16 KB
  __shared__ __align__(16) bf16 hA[16 * 512];     // 16 KB
  __shared__ float vbuf[4][16][17];
  __shared__ int lenL[8];

  // Weight slices f32 -> bf16 registers (wave = gate; B-frag n=l15).
  bf16x8 wih[16], whh[16];
  {
    int grow = wave * 512 + s * 16 + l15;
#pragma unroll
    for (int k = 0; k < 16; ++k) {
      const float* pw = Wih + (size_t)grow * 512 + k * 32 + quad * 8;
      const float* ph = Whh + (size_t)grow * 512 + k * 32 + quad * 8;
      wih[k] = cvt8v(*(const float4*)pw, *(const float4*)(pw + 4));
      whh[k] = cvt8v(*(const float4*)ph, *(const float4*)(ph + 4));
    }
  }
  const float bv = bih[wave * 512 + s * 16 + l15];
  if (tid < 8) lenL[tid] = lengths[b0 + tid];

  // Zero dead rows 8-15 of xA[0], xA[1], hA (one-time; 24KB total).
  {
    // 3 buffers x 8 rows x 512 bf16 = 12288 bf16 = 1536 x 16B chunks.
    for (int c = tid; c < 1536; c += 256) {
      int buf = c >> 9, r = (c >> 6) & 7, off = (c & 63) * 8;
      bf16* dst = (buf == 0) ? (xA[0] + (8 + r) * 512 + off)
                : (buf == 1) ? (xA[1] + (8 + r) * 512 + off)
                             : (hA + (8 + r) * 512 + off);
      *(ulonglong2*)dst = make_ulonglong2(0ull, 0ull);
    }
  }
  __syncthreads();

  // Cell mapping (threads 0-63): cb = group-local batch, cj = col pair.
  const int cb = tid >> 3, cj = (tid & 7) * 2;
  int lenR[2];
#pragma unroll
  for (int i = 0; i < 2; ++i) lenR[i] = lenL[(i * 256 + tid) >> 6];
  const int lenO = (tid < 64) ? lenL[cb] : 0;

  float creg0 = 0.f, creg1 = 0.f;
  u64* hb = hbuf + (size_t)dir * (2 * 32 * 256);

  // Prologue: load x(0), stage xA[0], then issue prefetch of x(1).
  float4 xp[2][2];
#pragma unroll
  for (int i = 0; i < 2; ++i) {
    int c = i * 256 + tid;
    int m = c >> 6, kbp = c & 63;          // m = group-local batch [0,8)
    int kb = kbp ^ (m & 7);
    int tr = (dir == 0) ? 0 : ((511 + lenR[i]) & 511);
    const float4* p = (const float4*)(x + ((size_t)(b0 + m) * 512 + tr) * 512 + kb * 8);
    xp[i][0] = p[0]; xp[i][1] = p[1];
  }
#pragma unroll
  for (int i = 0; i < 2; ++i) {
    int c = i * 256 + tid;
    *(bf16x8*)(xA[0] + c * 8) = cvt8v(xp[i][0], xp[i][1]);
  }
#pragma unroll
  for (int i = 0; i < 2; ++i) {
    int c = i * 256 + tid;
    int m = c >> 6, kbp = c & 63;
    int kb = kbp ^ (m & 7);
    int tr = (dir == 0) ? 1 : ((510 + lenR[i]) & 511);
    const float4* p = (const float4*)(x + ((size_t)(b0 + m) * 512 + tr) * 512 + kb * 8);
    xp[i][0] = p[0]; xp[i][1] = p[1];
  }
  bar_lgkm();  // xA[0] staged

  for (int step = 0; step < 512; ++step) {
    const int par = step & 1;
    const u64* hprev = hb + (size_t)par * (32 * 256);
    u64* hnext = hb + (size_t)(par ^ 1) * (32 * 256);
    const bf16* xcur = xA[par];
    bf16* xnxt = xA[par ^ 1];

    // ---- (1) stage xA(t+1) from regs ----
    if (step < 511) {
#pragma unroll
      for (int i = 0; i < 2; ++i) {
        int c = i * 256 + tid;
        *(bf16x8*)(xnxt + c * 8) = cvt8v(xp[i][0], xp[i][1]);
      }
    }
    // ---- (2) x(t+2) prefetch issue (R9 position) ----
    if (step < 510) {
#pragma unroll
      for (int i = 0; i < 2; ++i) {
        int c = i * 256 + tid;
        int m = c >> 6, kbp = c & 63;
        int kb = kbp ^ (m & 7);
        int tr = (dir == 0) ? (step + 2) : ((509 - step + lenR[i]) & 511);
        const float4* p = (const float4*)(x + ((size_t)(b0 + m) * 512 + tr) * 512 + kb * 8);
        xp[i][0] = p[0]; xp[i][1] = p[1];
      }
    }

    // ---- (3) x-part MFMAs: v = x@Wih^T + bias (one M=16 tile) ----
    f32x4 acc0 = {bv, bv, bv, bv};
#pragma unroll
    for (int k = 0; k < 16; ++k) {
      int kb = k * 4 + quad;
      int sw = (kb ^ (l15 & 7)) * 8;
      bf16x8 ax0 = *(const bf16x8*)(xcur + l15 * 512 + sw);
      acc0 = __builtin_amdgcn_mfma_f32_16x16x32_bf16(ax0, wih[k], acc0, 0, 0, 0);
    }
    __builtin_amdgcn_sched_barrier(0);

    // ---- (4) poll (R9 verbatim): coalesced dense batched re-sweep ----
    // wave w covers group-local batches [2w,2w+2); lane reads entries
    // lane+64j (512B contiguous per load instruction).
    u64 hv[2][4];
    {
      const unsigned target = (unsigned)step;
      while (true) {
#pragma unroll
        for (int b = 0; b < 2; ++b) {
          const u64* rp = hprev + (size_t)(b0 + wave * 2 + b) * 256 + lane;
#pragma unroll
          for (int j = 0; j < 4; ++j) hv[b][j] = ald64(rp + 64 * j);
        }
        int ok = 1;
#pragma unroll
        for (int b = 0; b < 2; ++b)
#pragma unroll
          for (int j = 0; j < 4; ++j)
            ok &= (int)((unsigned)(hv[b][j] >> 32) >= target);
        if (__all(ok)) break;
        __builtin_amdgcn_s_sleep(1);
      }
    }

    // ---- (5) stage payloads -> swizzled hA (R9 verbatim layout) ----
#pragma unroll
    for (int b = 0; b < 2; ++b) {
      int m = wave * 2 + b;                     // group-local batch [0,8)
#pragma unroll
      for (int j = 0; j < 4; ++j) {
        int b8 = (lane >> 2) + 16 * j;          // 8-col block of col 2*(lane+64j)
        int b8s = b8 ^ (m & 7);                 // same XOR swizzle as MFMA reads
        *(unsigned*)(hA + m * 512 + b8s * 8 + 2 * (lane & 3)) = (unsigned)hv[b][j];
      }
    }
    bar_lgkm();  // C: hA + xnxt visible (x prefetch rides through)

    // ---- (6) h-part MFMAs: v += h@Whh^T ----
#pragma unroll
    for (int k = 0; k < 16; ++k) {
      int kb = k * 4 + quad;
      int sw = (kb ^ (l15 & 7)) * 8;
      bf16x8 ah0 = *(const bf16x8*)(hA + l15 * 512 + sw);
      acc0 = __builtin_amdgcn_mfma_f32_16x16x32_bf16(ah0, whh[k], acc0, 0, 0, 0);
    }
#pragma unroll
    for (int r = 0; r < 4; ++r)
      vbuf[wave][quad * 4 + r][l15] = acc0[r];
    bar_lgkm();  // D: vbuf ready

    // ---- (7) cell + stores: threads 0-63 (8 batches x 8 col-pairs) ----
    if (tid < 64) {
      float i0 = vbuf[0][cb][cj],     f0 = vbuf[1][cb][cj];
      float g0 = vbuf[2][cb][cj],     o0 = vbuf[3][cb][cj];
      float i1 = vbuf[0][cb][cj + 1], f1 = vbuf[1][cb][cj + 1];
      float g1 = vbuf[2][cb][cj + 1], o1 = vbuf[3][cb][cj + 1];
      float c0 = sigmoidf_(f0) * creg0 + sigmoidf_(i0) * tanhf_(g0);
      float c1 = sigmoidf_(f1) * creg1 + sigmoidf_(i1) * tanhf_(g1);
      creg0 = c0; creg1 = c1;
      float h0 = tanhf_(c0) * sigmoidf_(o0);
      float h1 = tanhf_(c1) * sigmoidf_(o1);

      // tagged h store: coalesced 64B line per 8 lanes
      unsigned ulo = (unsigned)__builtin_bit_cast(unsigned short, (bf16)h0);
      unsigned uhi = (unsigned)__builtin_bit_cast(unsigned short, (bf16)h1);
      u64 pk = ((u64)(unsigned)(step + 1) << 32) | (u64)(ulo | (uhi << 16));
      ast64(hnext + (size_t)(b0 + cb) * 256 + s * 8 + (tid & 7), pk);

      // out store (coalesced 64B per 8-thread group)
      int tr = (dir == 0) ? step : ((511 - step + lenO) & 511);
      *(float2*)(out + (size_t)((b0 + cb) * 512 + tr) * 1024 + dir * 512 + s * 16 + cj) =
          make_float2(h0, h1);
    }
  }
}

extern "C" void kernel_launch(void* const* d_in, const int* in_sizes, int n_in,
                              void* d_out, int out_size, void* d_ws, size_t ws_size,
                              hipStream_t stream) {
  (void)in_sizes; (void)n_in; (void)out_size; (void)ws_size;
  const float* x    = (const float*)d_in[0];
  const int*   mask = (const int*)  d_in[1];
  const float* Wihf = (const float*)d_in[2];
  const float* bihf = (const float*)d_in[3];
  const float* Whhf = (const float*)d_in[4];
  const float* Wihb = (const float*)d_in[5];
  const float* bihb = (const float*)d_in[6];
  const float* Whhb = (const float*)d_in[7];
  float* out = (float*)d_out;

  char* ws = (char*)d_ws;
  u64* hbuf = (u64*)ws;                          // 2*2*32*256*8 = 262144 B
  int* lengths = (int*)(ws + 262144);            // 128 B
  const size_t head = 262144;

  hipMemsetAsync(d_ws, 0, head, stream);  // zero tags + h0 = c0 = 0 every call
  lengths_kernel<<<1, 256, 0, stream>>>(mask, lengths);
  lstm_fused<<<256, 256, 0, stream>>>(
      x, Wihf, bihf, Whhf, Wihb, bihb, Whhb, lengths, hbuf, out);
}